// Round 2
// baseline (204.407 us; speedup 1.0000x reference)
//
#include <hip/hip_runtime.h>

#define N_STFT 1025
#define N_MELS 128
#define BATCH 4
#define TIME 1024
#define MAX_ITER 20

// Extract per-frequency sparse filterbank structure: each fb row f has at most
// 2 nonzeros at adjacent mel indices (m0, m0+1) — triangular filters.
__global__ void imel_prep(const float* __restrict__ fb, int* __restrict__ m0f,
                          float* __restrict__ w0a, float* __restrict__ w1a) {
  const int w = threadIdx.x >> 6, l = threadIdx.x & 63;
  const int f = blockIdx.x * 4 + w;
  if (f >= N_STFT) return;
  const float* row = fb + (size_t)f * N_MELS;
  const unsigned long long mlo = __ballot(row[l] != 0.0f);
  const unsigned long long mhi = __ballot(row[l + 64] != 0.0f);
  if (l == 0) {
    int m0 = mlo ? __builtin_ctzll(mlo)
                 : (mhi ? 64 + __builtin_ctzll(mhi) : 0);
    if (m0 > N_MELS - 2) m0 = N_MELS - 2;   // all-zero rows (f=0, f=1024) -> w=0
    m0f[f] = m0;
    w0a[f] = row[m0];
    w1a[f] = row[m0 + 1];
  }
}

// r11 (retry — round-1 bench was an infra failure, no kernel verdict):
// ONE row per wave (was 2 packed in u64). Rationale: the 2-row kernel was
// latency-bound at 17% occupancy — 2048 waves total = 2 waves/SIMD; VALUBusy
// 47%, DS pipe ~45% incl. 20% bank-conflict cycles, neither saturated. 1 row
// per wave doubles resident waves to 16/CU (VGPR<=128 tier) while total DS
// BANK cycles stay constant (u64 ops -> u32 ops: half the bank cycles each,
// twice the waves). f32 ds_add_f32 atomics replace 2^24 fixed point: no
// cvt/pack VALU (~30% of hot-loop VALU gone) and stride-4 P uses all 32 banks
// (u64 stride-8 hit only the 16 even banks -> conflicts should ~halve).
// P stays WAVE-PRIVATE in LDS -> zero __syncthreads in the hot loop.
// inv prefactor folded out: work in buf' = buf/inv domain, so
//   g' = P·w - (mel·w),  buf' = 0.9 buf' + g',  spec -= (LR*inv)·buf'.
__global__ __launch_bounds__(512, 4) void imel_main(
    const float* __restrict__ melspec, const float* __restrict__ spec_init,
    const int* __restrict__ m0f, const float* __restrict__ w0a,
    const float* __restrict__ w1a, float* __restrict__ out) {
  __shared__ float s_P[8][N_MELS];   // per-wave private P row (f32)
  __shared__ float s_mel[8][N_MELS]; // staged mel columns (prologue only)
  __shared__ float s_out[8][1060];   // swizzle-padded: idx = f + (f>>5)

  const int tid = threadIdx.x;
  const int w   = tid >> 6;        // wave 0..7 -> row t0+w
  const int l   = tid & 63;
  // XCD swizzle: each XCD covers a contiguous (b,t) range -> melspec slice
  // per XCD ~0.5 MB (L2-resident) and adjacent output granules merge
  const int flat = (blockIdx.x & 7) * 64 + (blockIdx.x >> 3);
  const int b   = flat >> 7;          // 128 flats per batch
  const int t0  = (flat & 127) << 3;  // block covers t0..t0+7
  const int tA  = t0 + w;

  // ---- stage mel columns coalescedly: s_mel[r][m] = mel[b][m][t0+r] ----
  for (int i = tid; i < 8 * N_MELS; i += 512) {
    const int m = i >> 3, r = i & 7;
    s_mel[r][m] = melspec[((size_t)b * N_MELS + m) * TIME + t0 + r];
  }
  __syncthreads();

  // LR * inv = 0.3 * 2/(B*T): applied at the spec update (buf' domain)
  const float LRI = 0.3f * (2.0f / (BATCH * TIME)); // 1.46484375e-4f

  // per-lane static structure, f = 16*l + k  (f=1024: zero fb row -> copy)
  float rs[16], rb[16], rw0[16], rw1[16], cc[16];
  int rm[16];

  const float* srow = spec_init + (size_t)(b * TIME + tA) * N_STFT;
  const float* melW = &s_mel[w][0];
#pragma unroll
  for (int k = 0; k < 16; ++k) {
    const int f = (l << 4) + k;
    rs[k] = srow[f];
    const int m = m0f[f];
    rm[k] = m;
    const float w0 = w0a[f], w1 = w1a[f];
    rw0[k] = w0;
    rw1[k] = w1;
    cc[k] = -fmaf(melW[m], w0, melW[m + 1] * w1);  // -(mel·w), buf' domain
    rb[k] = 0.f;
  }
  const float rt = (l == 63) ? srow[1024] : 0.f;

  float* __restrict__ Pw = &s_P[w][0];
  Pw[l] = 0.f;
  Pw[l + 64] = 0.f;
  // wave-private P: no block barrier anywhere in the hot loop

  for (int it = 0; it < MAX_ITER; ++it) {
    // ---- forward: run-compacted scatter (ds_add_f32) ----
    // adv compares are loop-invariant (rm never changes) -> LICM hoists the
    // v_cmp results into SGPR masks; no VGPR cost.
    {
      float a0 = rs[0] * rw0[0], a1 = rs[0] * rw1[0];
#pragma unroll
      for (int k = 1; k < 16; ++k) {
        const bool adv = (rm[k] != rm[k - 1]);  // m0 monotone, step <= 1/bin
        if (adv) atomicAdd(&Pw[rm[k - 1]], a0);
        const float n0 = (adv ? a1 : a0) + rs[k] * rw0[k];
        a1 = (adv ? 0.f : a1) + rs[k] * rw1[k];
        a0 = n0;
      }
      atomicAdd(&Pw[rm[15]],     a0);
      atomicAdd(&Pw[rm[15] + 1], a1);
    }
    __builtin_amdgcn_wave_barrier();   // scheduling fence only
    // ---- backward: unconditional ds_read2_b32 per k (no select chain),
    //      momentum + clamp, all k independent ----
#pragma unroll
    for (int k = 0; k < 16; ++k) {
      const float p0 = Pw[rm[k]];        // pairs into ds_read2_b32
      const float p1 = Pw[rm[k] + 1];
      const float g = fmaf(p0, rw0[k], fmaf(p1, rw1[k], cc[k]));
      rb[k] = fmaf(0.9f, rb[k], g);
      rs[k] = fmaxf(fmaf(-LRI, rb[k], rs[k]), 0.f);
    }
    __builtin_amdgcn_wave_barrier();
    // ---- zero P for next iteration (same-wave DS program order) ----
    Pw[l] = 0.f;
    Pw[l + 64] = 0.f;
    __builtin_amdgcn_wave_barrier();
  }

  // ---- epilogue: transpose (f-major regs) -> (B, F, T) via swizzled LDS ----
#pragma unroll
  for (int k = 0; k < 16; ++k) {
    const int f = (l << 4) + k;
    s_out[w][f + (f >> 5)] = rs[k];
  }
  if (l == 63) s_out[w][1056] = rt;    // f=1024 -> 1024 + (1024>>5)
  __syncthreads();

  const int tl = tid & 7;    // t offset within the block's 8 rows
  const int fg = tid >> 3;   // 64 f phases
  float* obase = out + (size_t)b * N_STFT * TIME + t0 + tl;
  for (int f = fg; f < N_STFT; f += 64) {
    obase[(size_t)f * TIME] = s_out[tl][f + (f >> 5)];
  }
}

extern "C" void kernel_launch(void* const* d_in, const int* in_sizes, int n_in,
                              void* d_out, int out_size, void* d_ws, size_t ws_size,
                              hipStream_t stream) {
  const float* melspec = (const float*)d_in[0];
  const float* spec_init = (const float*)d_in[1];
  const float* fb = (const float*)d_in[2];
  float* out = (float*)d_out;

  int* m0f = (int*)d_ws;                          // 1025 ints
  float* w0a = (float*)((char*)d_ws + 5120);      // 1025 floats
  float* w1a = (float*)((char*)d_ws + 10240);     // 1025 floats

  imel_prep<<<dim3(257), dim3(256), 0, stream>>>(fb, m0f, w0a, w1a);
  imel_main<<<dim3(512), dim3(512), 0, stream>>>(melspec, spec_init, m0f, w0a, w1a, out);
}

// Round 3
// 203.458 us; speedup vs baseline: 1.0047x; 1.0047x over previous
//
#include <hip/hip_runtime.h>

#define N_STFT 1025
#define N_MELS 128
#define BATCH 4
#define TIME 1024
#define MAX_ITER 20

// Extract per-frequency sparse filterbank structure: each fb row f has at most
// 2 nonzeros at adjacent mel indices (m0, m0+1) — triangular filters.
__global__ void imel_prep(const float* __restrict__ fb, int* __restrict__ m0f,
                          float* __restrict__ w0a, float* __restrict__ w1a) {
  const int w = threadIdx.x >> 6, l = threadIdx.x & 63;
  const int f = blockIdx.x * 4 + w;
  if (f >= N_STFT) return;
  const float* row = fb + (size_t)f * N_MELS;
  const unsigned long long mlo = __ballot(row[l] != 0.0f);
  const unsigned long long mhi = __ballot(row[l + 64] != 0.0f);
  if (l == 0) {
    int m0 = mlo ? __builtin_ctzll(mlo)
                 : (mhi ? 64 + __builtin_ctzll(mhi) : 0);
    if (m0 > N_MELS - 2) m0 = N_MELS - 2;   // all-zero rows (f=0, f=1024) -> w=0
    m0f[f] = m0;
    w0a[f] = row[m0];
    w1a[f] = row[m0 + 1];
  }
}

// r12: r11 structure (1 row/wave, f32 ds_add_f32, wave-private P) with the
// register budget FIXED. r11's __launch_bounds__(512,4) = 128-reg budget made
// the allocator squeeze to 64 VGPR and spill the ~96-reg per-lane state:
// FETCH 9.3->20.9MB, WRITE 16.4->42.2MB (scratch), VALUBusy 47->15%, 140us.
// Same allocator pathology the prior session hit with (256,4). (512,2) gives
// the 256-reg budget under which it previously chose 120 regs; state here is
// ~110 regs -> lands <=128, so HW still runs 4 waves/SIMD and the grid
// (512 blocks x 8 waves = 16 waves/CU) fills that exactly.
// Occupancy half of r11 WAS validated: 17->39.7%, bank conflicts 5.8M->4.9M.
__global__ __launch_bounds__(512, 2) void imel_main(
    const float* __restrict__ melspec, const float* __restrict__ spec_init,
    const int* __restrict__ m0f, const float* __restrict__ w0a,
    const float* __restrict__ w1a, float* __restrict__ out) {
  __shared__ float s_P[8][N_MELS];   // per-wave private P row (f32)
  __shared__ float s_mel[8][N_MELS]; // staged mel columns (prologue only)
  __shared__ float s_out[8][1060];   // swizzle-padded: idx = f + (f>>5)

  const int tid = threadIdx.x;
  const int w   = tid >> 6;        // wave 0..7 -> row t0+w
  const int l   = tid & 63;
  // XCD swizzle: each XCD covers a contiguous (b,t) range -> melspec slice
  // per XCD ~0.5 MB (L2-resident) and adjacent output granules merge
  const int flat = (blockIdx.x & 7) * 64 + (blockIdx.x >> 3);
  const int b   = flat >> 7;          // 128 flats per batch
  const int t0  = (flat & 127) << 3;  // block covers t0..t0+7
  const int tA  = t0 + w;

  // ---- stage mel columns coalescedly: s_mel[r][m] = mel[b][m][t0+r] ----
  for (int i = tid; i < 8 * N_MELS; i += 512) {
    const int m = i >> 3, r = i & 7;
    s_mel[r][m] = melspec[((size_t)b * N_MELS + m) * TIME + t0 + r];
  }
  __syncthreads();

  // LR * inv = 0.3 * 2/(B*T): applied at the spec update (buf' domain)
  const float LRI = 0.3f * (2.0f / (BATCH * TIME)); // 1.46484375e-4f

  // per-lane static structure, f = 16*l + k  (f=1024: zero fb row -> copy)
  float rs[16], rb[16], rw0[16], rw1[16], cc[16];
  int rm[16];

  const float* srow = spec_init + (size_t)(b * TIME + tA) * N_STFT;
  const float* melW = &s_mel[w][0];
#pragma unroll
  for (int k = 0; k < 16; ++k) {
    const int f = (l << 4) + k;
    rs[k] = srow[f];
    const int m = m0f[f];
    rm[k] = m;
    const float w0 = w0a[f], w1 = w1a[f];
    rw0[k] = w0;
    rw1[k] = w1;
    cc[k] = -fmaf(melW[m], w0, melW[m + 1] * w1);  // -(mel·w), buf' domain
    rb[k] = 0.f;
  }
  const float rt = (l == 63) ? srow[1024] : 0.f;

  float* __restrict__ Pw = &s_P[w][0];
  Pw[l] = 0.f;
  Pw[l + 64] = 0.f;
  // wave-private P: no block barrier anywhere in the hot loop

  for (int it = 0; it < MAX_ITER; ++it) {
    // ---- forward: run-compacted scatter (ds_add_f32) ----
    // adv compares are loop-invariant (rm never changes) -> LICM hoists the
    // v_cmp results into SGPR masks; no VGPR cost.
    {
      float a0 = rs[0] * rw0[0], a1 = rs[0] * rw1[0];
#pragma unroll
      for (int k = 1; k < 16; ++k) {
        const bool adv = (rm[k] != rm[k - 1]);  // m0 monotone, step <= 1/bin
        if (adv) atomicAdd(&Pw[rm[k - 1]], a0);
        const float n0 = (adv ? a1 : a0) + rs[k] * rw0[k];
        a1 = (adv ? 0.f : a1) + rs[k] * rw1[k];
        a0 = n0;
      }
      atomicAdd(&Pw[rm[15]],     a0);
      atomicAdd(&Pw[rm[15] + 1], a1);
    }
    __builtin_amdgcn_wave_barrier();   // scheduling fence only
    // ---- backward: unconditional ds_read2_b32 per k (no select chain),
    //      momentum + clamp, all k independent ----
#pragma unroll
    for (int k = 0; k < 16; ++k) {
      const float p0 = Pw[rm[k]];        // pairs into ds_read2_b32
      const float p1 = Pw[rm[k] + 1];
      const float g = fmaf(p0, rw0[k], fmaf(p1, rw1[k], cc[k]));
      rb[k] = fmaf(0.9f, rb[k], g);
      rs[k] = fmaxf(fmaf(-LRI, rb[k], rs[k]), 0.f);
    }
    __builtin_amdgcn_wave_barrier();
    // ---- zero P for next iteration (same-wave DS program order) ----
    Pw[l] = 0.f;
    Pw[l + 64] = 0.f;
    __builtin_amdgcn_wave_barrier();
  }

  // ---- epilogue: transpose (f-major regs) -> (B, F, T) via swizzled LDS ----
#pragma unroll
  for (int k = 0; k < 16; ++k) {
    const int f = (l << 4) + k;
    s_out[w][f + (f >> 5)] = rs[k];
  }
  if (l == 63) s_out[w][1056] = rt;    // f=1024 -> 1024 + (1024>>5)
  __syncthreads();

  const int tl = tid & 7;    // t offset within the block's 8 rows
  const int fg = tid >> 3;   // 64 f phases
  float* obase = out + (size_t)b * N_STFT * TIME + t0 + tl;
  for (int f = fg; f < N_STFT; f += 64) {
    obase[(size_t)f * TIME] = s_out[tl][f + (f >> 5)];
  }
}

extern "C" void kernel_launch(void* const* d_in, const int* in_sizes, int n_in,
                              void* d_out, int out_size, void* d_ws, size_t ws_size,
                              hipStream_t stream) {
  const float* melspec = (const float*)d_in[0];
  const float* spec_init = (const float*)d_in[1];
  const float* fb = (const float*)d_in[2];
  float* out = (float*)d_out;

  int* m0f = (int*)d_ws;                          // 1025 ints
  float* w0a = (float*)((char*)d_ws + 5120);      // 1025 floats
  float* w1a = (float*)((char*)d_ws + 10240);     // 1025 floats

  imel_prep<<<dim3(257), dim3(256), 0, stream>>>(fb, m0f, w0a, w1a);
  imel_main<<<dim3(512), dim3(512), 0, stream>>>(melspec, spec_init, m0f, w0a, w1a, out);
}

// Round 4
// 202.579 us; speedup vs baseline: 1.0090x; 1.0043x over previous
//
#include <hip/hip_runtime.h>

#define N_STFT 1025
#define N_MELS 128
#define BATCH 4
#define TIME 1024
#define MAX_ITER 20

// Extract per-frequency sparse filterbank structure: each fb row f has at most
// 2 nonzeros at adjacent mel indices (m0, m0+1) — triangular filters.
__global__ void imel_prep(const float* __restrict__ fb, int* __restrict__ m0f,
                          float* __restrict__ w0a, float* __restrict__ w1a) {
  const int w = threadIdx.x >> 6, l = threadIdx.x & 63;
  const int f = blockIdx.x * 4 + w;
  if (f >= N_STFT) return;
  const float* row = fb + (size_t)f * N_MELS;
  const unsigned long long mlo = __ballot(row[l] != 0.0f);
  const unsigned long long mhi = __ballot(row[l + 64] != 0.0f);
  if (l == 0) {
    int m0 = mlo ? __builtin_ctzll(mlo)
                 : (mhi ? 64 + __builtin_ctzll(mhi) : 0);
    if (m0 > N_MELS - 2) m0 = N_MELS - 2;   // all-zero rows (f=0, f=1024) -> w=0
    m0f[f] = m0;
    w0a[f] = row[m0];
    w1a[f] = row[m0 + 1];
  }
}

// r13: 1-row/wave structure (validated r11/r12: occupancy 17->39%, conflicts
// 5.8M->4.9M) in r10's PROVEN register configuration. r11 (512,4): allocator
// targeted 8 w/SIMD -> 64 VGPR, spill to HBM (FETCH 21MB, 140us). r12 (512,2):
// allocator targeted 6 w/SIMD -> 80 VGPR, spill FITS IN L2 (FETCH clean but
// VALUBusy 15%, waves stalled ~200cy/scratch access, 137us). Lesson: the
// allocator picks an occupancy tier and ACCEPTS SPILLS to hit it; the only
// no-spill shape observed is (256,2) -> 120 VGPR. So: 256-thread blocks,
// 4 waves, ONE row per wave, block covers 4 t-rows, GRID 1024.
// Occupancy: VGPR~120 -> 4 w/SIMD; LDS 21KB -> 7 blocks; grid gives 4
// blocks/CU x 4 waves = 16 waves/CU = 4 w/SIMD resident (the r11 target).
// f32 ds_add_f32 P (stride-4: all 32 banks), wave-private -> no __syncthreads
// in hot loop. buf' domain: g' = P.w - (mel.w), spec -= LRI*buf'.
__global__ __launch_bounds__(256, 2) void imel_main(
    const float* __restrict__ melspec, const float* __restrict__ spec_init,
    const int* __restrict__ m0f, const float* __restrict__ w0a,
    const float* __restrict__ w1a, float* __restrict__ out) {
  __shared__ float s_P[4][N_MELS];   // per-wave private P row (f32)
  __shared__ float s_mel[4][N_MELS]; // staged mel columns (prologue only)
  __shared__ float s_out[4][1060];   // swizzle-padded: idx = f + (f>>5)

  const int tid = threadIdx.x;
  const int w   = tid >> 6;        // wave 0..3 -> row t0+w
  const int l   = tid & 63;
  // XCD swizzle for grid 1024: XCD x covers flats [x*128, x*128+128) = one
  // contiguous half-batch t-range -> melspec slice 256KB (L2-resident) and
  // adjacent blocks (adjacent t0, same XCD) merge 16B output granules in L2.
  const int flat = (blockIdx.x & 7) * 128 + (blockIdx.x >> 3);
  const int b   = flat >> 8;          // 256 flats per batch
  const int t0  = (flat & 255) << 2;  // block covers t0..t0+3
  const int tA  = t0 + w;

  // ---- stage mel columns: s_mel[r][m] = mel[b][m][t0+r] ----
  for (int i = tid; i < 4 * N_MELS; i += 256) {
    const int m = i >> 2, r = i & 3;
    s_mel[r][m] = melspec[((size_t)b * N_MELS + m) * TIME + t0 + r];
  }
  __syncthreads();

  // LR * inv = 0.3 * 2/(B*T): applied at the spec update (buf' domain)
  const float LRI = 0.3f * (2.0f / (BATCH * TIME)); // 1.46484375e-4f

  // per-lane static structure, f = 16*l + k  (f=1024: zero fb row -> copy)
  float rs[16], rb[16], rw0[16], rw1[16], cc[16];
  int rm[16];

  const float* srow = spec_init + (size_t)(b * TIME + tA) * N_STFT;
  const float* melW = &s_mel[w][0];
#pragma unroll
  for (int k = 0; k < 16; ++k) {
    const int f = (l << 4) + k;
    rs[k] = srow[f];
    const int m = m0f[f];
    rm[k] = m;
    const float w0 = w0a[f], w1 = w1a[f];
    rw0[k] = w0;
    rw1[k] = w1;
    cc[k] = -fmaf(melW[m], w0, melW[m + 1] * w1);  // -(mel.w), buf' domain
    rb[k] = 0.f;
  }
  const float rt = (l == 63) ? srow[1024] : 0.f;

  float* __restrict__ Pw = &s_P[w][0];
  Pw[l] = 0.f;
  Pw[l + 64] = 0.f;
  // wave-private P: no block barrier anywhere in the hot loop

  for (int it = 0; it < MAX_ITER; ++it) {
    // ---- forward: run-compacted scatter (ds_add_f32) ----
    {
      float a0 = rs[0] * rw0[0], a1 = rs[0] * rw1[0];
#pragma unroll
      for (int k = 1; k < 16; ++k) {
        const bool adv = (rm[k] != rm[k - 1]);  // m0 monotone, step <= 1/bin
        if (adv) atomicAdd(&Pw[rm[k - 1]], a0);
        const float n0 = (adv ? a1 : a0) + rs[k] * rw0[k];
        a1 = (adv ? 0.f : a1) + rs[k] * rw1[k];
        a0 = n0;
      }
      atomicAdd(&Pw[rm[15]],     a0);
      atomicAdd(&Pw[rm[15] + 1], a1);
    }
    __builtin_amdgcn_wave_barrier();   // scheduling fence only
    // ---- backward: unconditional ds_read2_b32 per k (no select chain),
    //      momentum + clamp, all k independent ----
#pragma unroll
    for (int k = 0; k < 16; ++k) {
      const float p0 = Pw[rm[k]];        // pairs into ds_read2_b32
      const float p1 = Pw[rm[k] + 1];
      const float g = fmaf(p0, rw0[k], fmaf(p1, rw1[k], cc[k]));
      rb[k] = fmaf(0.9f, rb[k], g);
      rs[k] = fmaxf(fmaf(-LRI, rb[k], rs[k]), 0.f);
    }
    __builtin_amdgcn_wave_barrier();
    // ---- zero P for next iteration (same-wave DS program order) ----
    Pw[l] = 0.f;
    Pw[l + 64] = 0.f;
    __builtin_amdgcn_wave_barrier();
  }

  // ---- epilogue: transpose (f-major regs) -> (B, F, T) via swizzled LDS ----
#pragma unroll
  for (int k = 0; k < 16; ++k) {
    const int f = (l << 4) + k;
    s_out[w][f + (f >> 5)] = rs[k];
  }
  if (l == 63) s_out[w][1056] = rt;    // f=1024 -> 1024 + (1024>>5)
  __syncthreads();

  const int tl = tid & 3;    // t offset within the block's 4 rows
  const int fg = tid >> 2;   // 64 f phases
  float* obase = out + (size_t)b * N_STFT * TIME + t0 + tl;
  for (int f = fg; f < N_STFT; f += 64) {
    obase[(size_t)f * TIME] = s_out[tl][f + (f >> 5)];
  }
}

extern "C" void kernel_launch(void* const* d_in, const int* in_sizes, int n_in,
                              void* d_out, int out_size, void* d_ws, size_t ws_size,
                              hipStream_t stream) {
  const float* melspec = (const float*)d_in[0];
  const float* spec_init = (const float*)d_in[1];
  const float* fb = (const float*)d_in[2];
  float* out = (float*)d_out;

  int* m0f = (int*)d_ws;                          // 1025 ints
  float* w0a = (float*)((char*)d_ws + 5120);      // 1025 floats
  float* w1a = (float*)((char*)d_ws + 10240);     // 1025 floats

  imel_prep<<<dim3(257), dim3(256), 0, stream>>>(fb, m0f, w0a, w1a);
  imel_main<<<dim3(1024), dim3(256), 0, stream>>>(melspec, spec_init, m0f, w0a, w1a, out);
}

// Round 5
// 201.610 us; speedup vs baseline: 1.0139x; 1.0048x over previous
//
#include <hip/hip_runtime.h>

#define N_STFT 1025
#define N_MELS 128
#define BATCH 4
#define TIME 1024
#define MAX_ITER 20

// Extract per-frequency sparse filterbank structure: each fb row f has at most
// 2 nonzeros at adjacent mel indices (m0, m0+1) — triangular filters.
__global__ void imel_prep(const float* __restrict__ fb, int* __restrict__ m0f,
                          float* __restrict__ w0a, float* __restrict__ w1a) {
  const int w = threadIdx.x >> 6, l = threadIdx.x & 63;
  const int f = blockIdx.x * 4 + w;
  if (f >= N_STFT) return;
  const float* row = fb + (size_t)f * N_MELS;
  const unsigned long long mlo = __ballot(row[l] != 0.0f);
  const unsigned long long mhi = __ballot(row[l + 64] != 0.0f);
  if (l == 0) {
    int m0 = mlo ? __builtin_ctzll(mlo)
                 : (mhi ? 64 + __builtin_ctzll(mhi) : 0);
    if (m0 > N_MELS - 2) m0 = N_MELS - 2;   // all-zero rows (f=0, f=1024) -> w=0
    m0f[f] = m0;
    w0a[f] = row[m0];
    w1a[f] = row[m0 + 1];
  }
}

// r14: identical body to r13; ONLY the occupancy attribute changes.
// Diagnosis across r10-r13: the AMDGPU scheduler targets the LDS-ALLOWED
// occupancy (absent an explicit waves_per_eu max) and spills registers to
// reach it. r10: 42.5KB LDS -> target 3 w/SIMD -> 120 VGPR no-spill (48us).
// r13: 21.5KB LDS -> target 7 -> squeezed to 80 VGPR, ~30 regs of per-lane
// state in scratch. Scratch is L2-resident (FETCH/WRITE clean) but ~200cy
// per reload x ~64/iter x 20 iters ~= the whole 134us at VALUBusy 15%.
// amdgpu_waves_per_eu(2,4): budget 256 (min=2), target CAPPED at 4 w/SIMD.
// State ~110 regs < 128 -> no spill, and HW runs 4 w/SIMD = grid's
// 4 blocks/CU x 4 waves exactly.
__global__ __launch_bounds__(256)
__attribute__((amdgpu_waves_per_eu(2, 4))) void imel_main(
    const float* __restrict__ melspec, const float* __restrict__ spec_init,
    const int* __restrict__ m0f, const float* __restrict__ w0a,
    const float* __restrict__ w1a, float* __restrict__ out) {
  __shared__ float s_P[4][N_MELS];   // per-wave private P row (f32)
  __shared__ float s_mel[4][N_MELS]; // staged mel columns (prologue only)
  __shared__ float s_out[4][1060];   // swizzle-padded: idx = f + (f>>5)

  const int tid = threadIdx.x;
  const int w   = tid >> 6;        // wave 0..3 -> row t0+w
  const int l   = tid & 63;
  // XCD swizzle for grid 1024: XCD x covers flats [x*128, x*128+128) = one
  // contiguous half-batch t-range -> melspec slice 256KB (L2-resident) and
  // adjacent blocks (adjacent t0, same XCD) merge 16B output granules in L2.
  const int flat = (blockIdx.x & 7) * 128 + (blockIdx.x >> 3);
  const int b   = flat >> 8;          // 256 flats per batch
  const int t0  = (flat & 255) << 2;  // block covers t0..t0+3
  const int tA  = t0 + w;

  // ---- stage mel columns: s_mel[r][m] = mel[b][m][t0+r] ----
  for (int i = tid; i < 4 * N_MELS; i += 256) {
    const int m = i >> 2, r = i & 3;
    s_mel[r][m] = melspec[((size_t)b * N_MELS + m) * TIME + t0 + r];
  }
  __syncthreads();

  // LR * inv = 0.3 * 2/(B*T): applied at the spec update (buf' domain)
  const float LRI = 0.3f * (2.0f / (BATCH * TIME)); // 1.46484375e-4f

  // per-lane static structure, f = 16*l + k  (f=1024: zero fb row -> copy)
  float rs[16], rb[16], rw0[16], rw1[16], cc[16];
  int rm[16];

  const float* srow = spec_init + (size_t)(b * TIME + tA) * N_STFT;
  const float* melW = &s_mel[w][0];
#pragma unroll
  for (int k = 0; k < 16; ++k) {
    const int f = (l << 4) + k;
    rs[k] = srow[f];
    const int m = m0f[f];
    rm[k] = m;
    const float w0 = w0a[f], w1 = w1a[f];
    rw0[k] = w0;
    rw1[k] = w1;
    cc[k] = -fmaf(melW[m], w0, melW[m + 1] * w1);  // -(mel.w), buf' domain
    rb[k] = 0.f;
  }
  const float rt = (l == 63) ? srow[1024] : 0.f;

  float* __restrict__ Pw = &s_P[w][0];
  Pw[l] = 0.f;
  Pw[l + 64] = 0.f;
  // wave-private P: no block barrier anywhere in the hot loop

  for (int it = 0; it < MAX_ITER; ++it) {
    // ---- forward: run-compacted scatter (ds_add_f32) ----
    {
      float a0 = rs[0] * rw0[0], a1 = rs[0] * rw1[0];
#pragma unroll
      for (int k = 1; k < 16; ++k) {
        const bool adv = (rm[k] != rm[k - 1]);  // m0 monotone, step <= 1/bin
        if (adv) atomicAdd(&Pw[rm[k - 1]], a0);
        const float n0 = (adv ? a1 : a0) + rs[k] * rw0[k];
        a1 = (adv ? 0.f : a1) + rs[k] * rw1[k];
        a0 = n0;
      }
      atomicAdd(&Pw[rm[15]],     a0);
      atomicAdd(&Pw[rm[15] + 1], a1);
    }
    __builtin_amdgcn_wave_barrier();   // scheduling fence only
    // ---- backward: unconditional ds_read2_b32 per k (no select chain),
    //      momentum + clamp, all k independent ----
#pragma unroll
    for (int k = 0; k < 16; ++k) {
      const float p0 = Pw[rm[k]];        // pairs into ds_read2_b32
      const float p1 = Pw[rm[k] + 1];
      const float g = fmaf(p0, rw0[k], fmaf(p1, rw1[k], cc[k]));
      rb[k] = fmaf(0.9f, rb[k], g);
      rs[k] = fmaxf(fmaf(-LRI, rb[k], rs[k]), 0.f);
    }
    __builtin_amdgcn_wave_barrier();
    // ---- zero P for next iteration (same-wave DS program order) ----
    Pw[l] = 0.f;
    Pw[l + 64] = 0.f;
    __builtin_amdgcn_wave_barrier();
  }

  // ---- epilogue: transpose (f-major regs) -> (B, F, T) via swizzled LDS ----
#pragma unroll
  for (int k = 0; k < 16; ++k) {
    const int f = (l << 4) + k;
    s_out[w][f + (f >> 5)] = rs[k];
  }
  if (l == 63) s_out[w][1056] = rt;    // f=1024 -> 1024 + (1024>>5)
  __syncthreads();

  const int tl = tid & 3;    // t offset within the block's 4 rows
  const int fg = tid >> 2;   // 64 f phases
  float* obase = out + (size_t)b * N_STFT * TIME + t0 + tl;
  for (int f = fg; f < N_STFT; f += 64) {
    obase[(size_t)f * TIME] = s_out[tl][f + (f >> 5)];
  }
}

extern "C" void kernel_launch(void* const* d_in, const int* in_sizes, int n_in,
                              void* d_out, int out_size, void* d_ws, size_t ws_size,
                              hipStream_t stream) {
  const float* melspec = (const float*)d_in[0];
  const float* spec_init = (const float*)d_in[1];
  const float* fb = (const float*)d_in[2];
  float* out = (float*)d_out;

  int* m0f = (int*)d_ws;                          // 1025 ints
  float* w0a = (float*)((char*)d_ws + 5120);      // 1025 floats
  float* w1a = (float*)((char*)d_ws + 10240);     // 1025 floats

  imel_prep<<<dim3(257), dim3(256), 0, stream>>>(fb, m0f, w0a, w1a);
  imel_main<<<dim3(1024), dim3(256), 0, stream>>>(melspec, spec_init, m0f, w0a, w1a, out);
}

// Round 6
// 116.500 us; speedup vs baseline: 1.7546x; 1.7305x over previous
//
#include <hip/hip_runtime.h>

#define N_STFT 1025
#define N_MELS 128
#define BATCH 4
#define TIME 1024
#define MAX_ITER 20

typedef unsigned int u32;

// Extract per-frequency sparse filterbank structure: each fb row f has at most
// 2 nonzeros at adjacent mel indices (m0, m0+1) — triangular filters.
__global__ void imel_prep(const float* __restrict__ fb, int* __restrict__ m0f,
                          float* __restrict__ w0a, float* __restrict__ w1a) {
  const int w = threadIdx.x >> 6, l = threadIdx.x & 63;
  const int f = blockIdx.x * 4 + w;
  if (f >= N_STFT) return;
  const float* row = fb + (size_t)f * N_MELS;
  const unsigned long long mlo = __ballot(row[l] != 0.0f);
  const unsigned long long mhi = __ballot(row[l + 64] != 0.0f);
  if (l == 0) {
    int m0 = mlo ? __builtin_ctzll(mlo)
                 : (mhi ? 64 + __builtin_ctzll(mhi) : 0);
    if (m0 > N_MELS - 2) m0 = N_MELS - 2;   // all-zero rows (f=0, f=1024) -> w=0
    m0f[f] = m0;
    w0a[f] = row[m0];
    w1a[f] = row[m0 + 1];
  }
}

// r15: ROOT CAUSE of r11-r14 (all ~134us, VALUBusy 15%, VGPR 80): plain
// atomicAdd(float*) on LDS compiles to a ds_cmpst CAS LOOP (ds_add_f32
// flushes denormals, so hipcc won't emit it without -munsafe-fp-atomics).
// 17 contended CAS loops/iter serialized the wave (~120cy LDS round-trip per
// retry) AND their branchy live ranges made the allocator spill the 16-wide
// arrays at 80 VGPR regardless of budget — why (512,2)/(256,2)/waves_per_eu
// all produced identical counters. r10 was immune: integer u64 atomicAdd is
// a native single ds_add_u64.
// Fix: 1-row/wave structure (validated) + u32 FIXED-POINT P (native
// ds_add_u32, straight-line). Numerics = r10's proven scheme: 2^24 scale,
// P <= ~84*2^24 < 2^31 (same headroom as r10's packed halves).
// g' = (p0*rw0 + p1*rw1)*2^-48 + cc  (rw ARE pre-scaled by 2^24), buf'
// domain: spec -= LRI*buf'.
__global__ __launch_bounds__(256)
__attribute__((amdgpu_waves_per_eu(2, 4))) void imel_main(
    const float* __restrict__ melspec, const float* __restrict__ spec_init,
    const int* __restrict__ m0f, const float* __restrict__ w0a,
    const float* __restrict__ w1a, float* __restrict__ out) {
  __shared__ u32   s_P[4][N_MELS];   // per-wave private P row (u32 fixed pt)
  __shared__ float s_mel[4][N_MELS]; // staged mel columns (prologue only)
  __shared__ float s_out[4][1060];   // swizzle-padded: idx = f + (f>>5)

  const int tid = threadIdx.x;
  const int w   = tid >> 6;        // wave 0..3 -> row t0+w
  const int l   = tid & 63;
  // XCD swizzle for grid 1024: XCD x covers flats [x*128, x*128+128) = one
  // contiguous quarter-batch t-range -> melspec slice L2-resident and
  // adjacent blocks (adjacent t0, same XCD) merge 16B output granules in L2.
  const int flat = (blockIdx.x & 7) * 128 + (blockIdx.x >> 3);
  const int b   = flat >> 8;          // 256 flats per batch
  const int t0  = (flat & 255) << 2;  // block covers t0..t0+3
  const int tA  = t0 + w;

  // ---- stage mel columns: s_mel[r][m] = mel[b][m][t0+r] ----
  for (int i = tid; i < 4 * N_MELS; i += 256) {
    const int m = i >> 2, r = i & 3;
    s_mel[r][m] = melspec[((size_t)b * N_MELS + m) * TIME + t0 + r];
  }
  __syncthreads();

  const float SCALE = 16777216.0f;                 // 2^24 fixed point
  const float INV48 = 3.5527136788005009e-15f;     // 2^-48 (rw are 2^24-scaled)
  // LR * inv = 0.3 * 2/(B*T): applied at the spec update (buf' domain)
  const float LRI = 0.3f * (2.0f / (BATCH * TIME)); // 1.46484375e-4f

  // per-lane static structure, f = 16*l + k  (f=1024: zero fb row -> copy)
  float rs[16], rb[16], rw0[16], rw1[16], cc[16];
  int rm[16];

  const float* srow = spec_init + (size_t)(b * TIME + tA) * N_STFT;
  const float* melW = &s_mel[w][0];
#pragma unroll
  for (int k = 0; k < 16; ++k) {
    const int f = (l << 4) + k;
    rs[k] = srow[f];
    const int m = m0f[f];
    rm[k] = m;
    const float w0 = w0a[f], w1 = w1a[f];
    rw0[k] = w0 * SCALE;
    rw1[k] = w1 * SCALE;
    cc[k] = -fmaf(melW[m], w0, melW[m + 1] * w1);  // -(mel.w), buf' domain
    rb[k] = 0.f;
  }
  const float rt = (l == 63) ? srow[1024] : 0.f;

  u32* __restrict__ Pw = &s_P[w][0];
  Pw[l] = 0u;
  Pw[l + 64] = 0u;
  // wave-private P: no block barrier anywhere in the hot loop

  for (int it = 0; it < MAX_ITER; ++it) {
    // ---- forward: run-compacted scatter (native ds_add_u32) ----
    {
      float a0 = rs[0] * rw0[0], a1 = rs[0] * rw1[0];
#pragma unroll
      for (int k = 1; k < 16; ++k) {
        const bool adv = (rm[k] != rm[k - 1]);  // m0 monotone, step <= 1/bin
        if (adv) atomicAdd(&Pw[rm[k - 1]], (u32)__float2int_rn(a0));
        const float n0 = (adv ? a1 : a0) + rs[k] * rw0[k];
        a1 = (adv ? 0.f : a1) + rs[k] * rw1[k];
        a0 = n0;
      }
      atomicAdd(&Pw[rm[15]],     (u32)__float2int_rn(a0));
      atomicAdd(&Pw[rm[15] + 1], (u32)__float2int_rn(a1));
    }
    __builtin_amdgcn_wave_barrier();   // scheduling fence only
    // ---- backward: unconditional ds_read2_b32 per k (no select chain),
    //      momentum + clamp, all k independent ----
#pragma unroll
    for (int k = 0; k < 16; ++k) {
      const u32 q0 = Pw[rm[k]];        // pairs into ds_read2_b32
      const u32 q1 = Pw[rm[k] + 1];
      const float p0 = (float)(int)q0; // P < 2^31 -> signed cvt exact path
      const float p1 = (float)(int)q1;
      const float t  = fmaf(p0, rw0[k], p1 * rw1[k]);
      const float g  = fmaf(t, INV48, cc[k]);
      rb[k] = fmaf(0.9f, rb[k], g);
      rs[k] = fmaxf(fmaf(-LRI, rb[k], rs[k]), 0.f);
    }
    __builtin_amdgcn_wave_barrier();
    // ---- zero P for next iteration (same-wave DS program order) ----
    Pw[l] = 0u;
    Pw[l + 64] = 0u;
    __builtin_amdgcn_wave_barrier();
  }

  // ---- epilogue: transpose (f-major regs) -> (B, F, T) via swizzled LDS ----
#pragma unroll
  for (int k = 0; k < 16; ++k) {
    const int f = (l << 4) + k;
    s_out[w][f + (f >> 5)] = rs[k];
  }
  if (l == 63) s_out[w][1056] = rt;    // f=1024 -> 1024 + (1024>>5)
  __syncthreads();

  const int tl = tid & 3;    // t offset within the block's 4 rows
  const int fg = tid >> 2;   // 64 f phases
  float* obase = out + (size_t)b * N_STFT * TIME + t0 + tl;
  for (int f = fg; f < N_STFT; f += 64) {
    obase[(size_t)f * TIME] = s_out[tl][f + (f >> 5)];
  }
}

extern "C" void kernel_launch(void* const* d_in, const int* in_sizes, int n_in,
                              void* d_out, int out_size, void* d_ws, size_t ws_size,
                              hipStream_t stream) {
  const float* melspec = (const float*)d_in[0];
  const float* spec_init = (const float*)d_in[1];
  const float* fb = (const float*)d_in[2];
  float* out = (float*)d_out;

  int* m0f = (int*)d_ws;                          // 1025 ints
  float* w0a = (float*)((char*)d_ws + 5120);      // 1025 floats
  float* w1a = (float*)((char*)d_ws + 10240);     // 1025 floats

  imel_prep<<<dim3(257), dim3(256), 0, stream>>>(fb, m0f, w0a, w1a);
  imel_main<<<dim3(1024), dim3(256), 0, stream>>>(melspec, spec_init, m0f, w0a, w1a, out);
}